// Round 13
// baseline (421.523 us; speedup 1.0000x reference)
//
#include <hip/hip_runtime.h>

#define N_NODESC 50000
#define N_EDGESC 640000
#define N_GRAPHSC 64
#define HIDC 128
#define LN_EPSF 1e-5f
#define POOL_SPLIT 16
#define SCAN_NB 49   // 49*1024 = 50176 >= 50000
#define EGRID ((N_EDGESC + 255) / 256)
#define NGRID_GB ((N_NODESC + 255) / 256)
#define PREP_ELEMS (8192 + 49152 + 49152)   // ninWb + cW1b + cW2b
#define WPREP_NB ((PREP_ELEMS + 255) / 256) // 416

typedef short bf16x8 __attribute__((ext_vector_type(8)));
typedef float f32x4 __attribute__((ext_vector_type(4)));

// ---------- helpers ----------
static __device__ __forceinline__ unsigned ord_enc(float f) {
  unsigned u = __float_as_uint(f);
  return (u & 0x80000000u) ? ~u : (u | 0x80000000u);
}
static __device__ __forceinline__ float ord_dec(unsigned u) {
  return __uint_as_float((u & 0x80000000u) ? (u ^ 0x80000000u) : ~u);
}
static __device__ __forceinline__ unsigned short f2bf(float x) {
  unsigned u = __float_as_uint(x);
  u += 0x7fffu + ((u >> 16) & 1u);
  return (unsigned short)(u >> 16);
}
static __device__ __forceinline__ float bf2f(unsigned short b) {
  return __uint_as_float(((unsigned)b) << 16);
}

static __device__ __forceinline__ void mlp16(float in0, float in1, float in2,
    const float* __restrict__ W1, const float* __restrict__ b1,
    const float* __restrict__ g, const float* __restrict__ be,
    const float* __restrict__ W2, const float* __restrict__ b2,
    float* __restrict__ out) {
  float h[16];
  float s1 = 0.f, s2 = 0.f;
#pragma unroll
  for (int j = 0; j < 16; ++j) {
    float v = b1[j] + W1[j*3+0]*in0 + W1[j*3+1]*in1 + W1[j*3+2]*in2;
    v = fmaxf(v, 0.f);
    h[j] = v; s1 += v; s2 += v*v;
  }
  float mu = s1 * (1.f/16.f);
  float var = fmaxf(s2 * (1.f/16.f) - mu*mu, 0.f);
  float rs = rsqrtf(var + LN_EPSF);
  float z[16];
#pragma unroll
  for (int j = 0; j < 16; ++j) z[j] = (h[j]-mu)*rs*g[j] + be[j];
#pragma unroll
  for (int j = 0; j < 16; ++j) {
    float v = b2[j];
#pragma unroll
    for (int k = 0; k < 16; ++k) v += W2[j*16+k]*z[k];
    out[j] = v;
  }
}

// ---------- hist (edges) + gbound (nodes) + weight bf16 prep in one dispatch ----------
__global__ __launch_bounds__(256) void hist_gbound_kernel(const int* __restrict__ ei,
    int* __restrict__ deg, const int* __restrict__ batch, int* __restrict__ gstart,
    const float* __restrict__ ninW, unsigned short* __restrict__ ninWb,
    const float* __restrict__ cW1, unsigned short* __restrict__ cW1b,
    const float* __restrict__ cW2, unsigned short* __restrict__ cW2b) {
  const int b = blockIdx.x;
  if (b < EGRID) {
    int e = b * 256 + threadIdx.x;
    if (e < N_EDGESC) atomicAdd(&deg[ei[N_EDGESC + e]], 1);
  } else if (b < EGRID + NGRID_GB) {
    int i = (b - EGRID) * 256 + threadIdx.x;
    if (i >= N_NODESC) return;
    int bb = batch[i];
    int prev = (i == 0) ? -1 : batch[i-1];
    for (int g = prev + 1; g <= bb; ++g) gstart[g] = i;
    if (i == N_NODESC - 1) {
      for (int g = bb + 1; g <= N_GRAPHSC; ++g) gstart[g] = N_NODESC;
    }
  } else {
    int i = (b - EGRID - NGRID_GB) * 256 + threadIdx.x;
    if (i < 8192) {
      int f = i >> 6, k = i & 63;
      ninWb[i] = (k < 45) ? f2bf(ninW[f*45 + k]) : (unsigned short)0;
    } else if (i < 8192 + 49152) {
      int j = i - 8192;
      cW1b[j] = f2bf(cW1[j]);
    } else if (i < PREP_ELEMS) {
      int j = i - 8192 - 49152;
      cW2b[j] = f2bf(cW2[j]);
    }
  }
}

// ---------- scan phase 1 ----------
__global__ __launch_bounds__(1024) void scan1_kernel(const int* __restrict__ deg,
                                                     int* __restrict__ incl,
                                                     int* __restrict__ bsum) {
  const int b = blockIdx.x, t = threadIdx.x;
  const int i = b * 1024 + t;
  const int lane = t & 63, w = t >> 6;
  int v = (i < N_NODESC) ? deg[i] : 0;
#pragma unroll
  for (int off = 1; off < 64; off <<= 1) {
    int n = __shfl_up(v, off);
    if (lane >= off) v += n;
  }
  __shared__ int wsum[16];
  if (lane == 63) wsum[w] = v;
  __syncthreads();
  if (t == 0) {
    int run = 0;
#pragma unroll
    for (int k = 0; k < 16; ++k) { int x = wsum[k]; wsum[k] = run; run += x; }
  }
  __syncthreads();
  v += wsum[w];
  if (i < N_NODESC) incl[i] = v;
  if (t == 1023) bsum[b] = v;
}

// ---------- scan phases 2+3 fused ----------
__global__ __launch_bounds__(1024) void scan23_kernel(const int* __restrict__ deg,
                                                      const int* __restrict__ bsum,
                                                      int* __restrict__ rowptr,
                                                      int* __restrict__ cursor) {
  __shared__ int ex[SCAN_NB + 1];
  const int b = blockIdx.x, t = threadIdx.x;
  if (t < 64) {
    int v = (t < SCAN_NB) ? bsum[t] : 0;
    const int orig = v;
#pragma unroll
    for (int off = 1; off < 64; off <<= 1) {
      int n = __shfl_up(v, off);
      if (t >= off) v += n;
    }
    if (t < SCAN_NB) ex[t] = v - orig;
    if (t == SCAN_NB - 1) ex[SCAN_NB] = v;
  }
  __syncthreads();
  const int i = b * 1024 + t;
  if (i < N_NODESC) {
    int excl = rowptr[i] - deg[i] + ex[b];
    rowptr[i] = excl;
    cursor[i] = excl;
  }
  if (b == 0 && t == 0) rowptr[N_NODESC] = ex[SCAN_NB];
}

__global__ __launch_bounds__(256) void scatter_kernel(const int* __restrict__ ei,
                                                      int* __restrict__ cursor,
                                                      int* __restrict__ esrc) {
  int e = blockIdx.x * 256 + threadIdx.x;
  if (e < N_EDGESC) {
    int d = ei[N_EDGESC + e];
    int slot = atomicAdd(&cursor[d], 1);
    esrc[slot] = ei[e];
  }
}

// ---------- encoder (MFMA): parallel small MLPs -> bf16 A tile -> MFMA vs ninWb ----------
__global__ __launch_bounds__(256, 4) void enc_mfma_kernel(
    const float* __restrict__ x,
    const float* __restrict__ aW1, const float* __restrict__ ab1,
    const float* __restrict__ ag,  const float* __restrict__ abe,
    const float* __restrict__ aW2, const float* __restrict__ ab2,
    const float* __restrict__ oW1, const float* __restrict__ ob1,
    const float* __restrict__ og,  const float* __restrict__ obe,
    const float* __restrict__ oW2, const float* __restrict__ ob2,
    const unsigned short* __restrict__ ninWb, const float* __restrict__ ninb,
    unsigned short* __restrict__ Hb) {
  __shared__ unsigned short Ab[64*136];
  const int t = threadIdx.x;
  const int nb = blockIdx.x * 64;

  if (t < 192) {
    const int n = t & 63;
    const int gn = nb + n;
    const int grp = t >> 6;
    if (gn < N_NODESC) {
      const float* xr = x + gn * 19;
      if (grp == 0) {
        float z[16];
        mlp16(xr[9], xr[10], xr[11], aW1, ab1, ag, abe, aW2, ab2, z);
#pragma unroll
        for (int k = 0; k < 16; ++k) Ab[n*136 + 13 + k] = f2bf(z[k]);
      } else if (grp == 1) {
        float z[16];
        mlp16(xr[12], xr[13], xr[14], oW1, ob1, og, obe, oW2, ob2, z);
#pragma unroll
        for (int k = 0; k < 16; ++k) Ab[n*136 + 29 + k] = f2bf(z[k]);
      } else {
#pragma unroll
        for (int k = 0; k < 9; ++k) Ab[n*136 + k] = f2bf(xr[k]);
#pragma unroll
        for (int k = 0; k < 4; ++k) Ab[n*136 + 9 + k] = f2bf(xr[15 + k]);
#pragma unroll
        for (int k = 45; k < 64; ++k) Ab[n*136 + k] = 0;
      }
    } else {
      if (grp == 0) {
#pragma unroll
        for (int k = 0; k < 16; ++k) Ab[n*136 + 13 + k] = 0;
      } else if (grp == 1) {
#pragma unroll
        for (int k = 0; k < 16; ++k) Ab[n*136 + 29 + k] = 0;
      } else {
#pragma unroll
        for (int k = 0; k < 13; ++k) Ab[n*136 + k] = 0;
#pragma unroll
        for (int k = 45; k < 64; ++k) Ab[n*136 + k] = 0;
      }
    }
  }
  __syncthreads();

  const int lane = t & 63, wv = t >> 6;
  const int quad = lane >> 4, l16 = lane & 15;
  const int arow = (wv*16 + l16)*136 + quad*8;
  f32x4 acc[8];
#pragma unroll
  for (int ft = 0; ft < 8; ++ft) acc[ft] = (f32x4){0.f,0.f,0.f,0.f};
#pragma unroll
  for (int ks = 0; ks < 2; ++ks) {
    bf16x8 a = *(const bf16x8*)(const void*)&Ab[arow + ks*32];
#pragma unroll
    for (int ft = 0; ft < 8; ++ft) {
      bf16x8 bfr = *(const bf16x8*)&ninWb[(ft*16 + l16)*64 + quad*8 + ks*32];
      acc[ft] = __builtin_amdgcn_mfma_f32_16x16x32_bf16(a, bfr, acc[ft], 0, 0, 0);
    }
  }
  float bb[8];
#pragma unroll
  for (int ft = 0; ft < 8; ++ft) bb[ft] = ninb[ft*16 + l16];
  __syncthreads();
#pragma unroll
  for (int r = 0; r < 4; ++r) {
    int nloc = wv*16 + quad*4 + r;
#pragma unroll
    for (int ft = 0; ft < 8; ++ft)
      Ab[nloc*136 + ft*16 + l16] = f2bf(acc[ft][r] + bb[ft]);
  }
  __syncthreads();
#pragma unroll
  for (int i = 0; i < 4; ++i) {
    int chunk = t + i*256;
    int n = chunk >> 4, c8 = chunk & 15;
    int gn = nb + n;
    if (gn < N_NODESC)
      *(bf16x8*)&Hb[gn*HIDC + c8*8] = *(const bf16x8*)&Ab[n*136 + c8*8];
  }
}

// ---------- aggregation (bf16, standalone for max gather parallelism) ----------
__global__ __launch_bounds__(128) void agg_kernel(const unsigned short* __restrict__ Hb,
    const int* __restrict__ rowptr, const int* __restrict__ esrc,
    const float* __restrict__ epsp, unsigned short* __restrict__ Mb) {
  const int t = threadIdx.x;
  const int c8 = t & 15;
  const int v  = t >> 4;
  const int node = blockIdx.x * 8 + v;
  if (node >= N_NODESC) return;
  const float e1 = 1.0f + epsp[0];
  bf16x8 h = *(const bf16x8*)&Hb[node*HIDC + c8*8];
  float acc[8];
#pragma unroll
  for (int k = 0; k < 8; ++k) acc[k] = 0.f;
  int s = rowptr[node];
  const int e = rowptr[node+1];
  for (; s + 4 <= e; s += 4) {
    int i0 = esrc[s], i1 = esrc[s+1], i2 = esrc[s+2], i3 = esrc[s+3];
    bf16x8 x0 = *(const bf16x8*)&Hb[i0*HIDC + c8*8];
    bf16x8 x1 = *(const bf16x8*)&Hb[i1*HIDC + c8*8];
    bf16x8 x2 = *(const bf16x8*)&Hb[i2*HIDC + c8*8];
    bf16x8 x3 = *(const bf16x8*)&Hb[i3*HIDC + c8*8];
#pragma unroll
    for (int k = 0; k < 8; ++k)
      acc[k] += (bf2f((unsigned short)x0[k]) + bf2f((unsigned short)x1[k]))
              + (bf2f((unsigned short)x2[k]) + bf2f((unsigned short)x3[k]));
  }
  for (; s < e; ++s) {
    bf16x8 x0 = *(const bf16x8*)&Hb[esrc[s]*HIDC + c8*8];
#pragma unroll
    for (int k = 0; k < 8; ++k) acc[k] += bf2f((unsigned short)x0[k]);
  }
  bf16x8 m8;
#pragma unroll
  for (int k = 0; k < 8; ++k)
    m8[k] = (short)f2bf(e1*bf2f((unsigned short)h[k]) + acc[k]);
  *(bf16x8*)&Mb[node*HIDC + c8*8] = m8;
}

// ---------- GEMM pair: B fragments from global bf16 W (L1-resident); A/T in LDS ----------
// bounds(256,4): VGPR cap 128 (room to prefetch B), LDS 17.4KB -> 4 blocks/CU.
__global__ __launch_bounds__(256, 4) void gemmpair_kernel(
    const unsigned short* __restrict__ Mb,
    const unsigned short* __restrict__ Hin,
    const unsigned short* __restrict__ W1b, const float* __restrict__ b1,
    const float* __restrict__ g1, const float* __restrict__ be1,
    const unsigned short* __restrict__ W2b, const float* __restrict__ b2,
    const float* __restrict__ lng, const float* __restrict__ lnb,
    unsigned short* __restrict__ Hout) {
  __shared__ unsigned short Ab[64*136];   // M tile -> T tile -> OUT tile
  const int t = threadIdx.x;
  const int nb = blockIdx.x * 64;

  // stage A tile from Mb
#pragma unroll
  for (int i = 0; i < 4; ++i) {
    int chunk = t + i*256;
    int n = chunk >> 4, c8 = chunk & 15;
    int gn = nb + n;
    bf16x8 v = {0,0,0,0,0,0,0,0};
    if (gn < N_NODESC) v = *(const bf16x8*)&Mb[gn*HIDC + c8*8];
    *(bf16x8*)&Ab[n*136 + c8*8] = v;
  }
  __syncthreads();

  const int lane = t & 63, wv = t >> 6;
  const int quad = lane >> 4, l16 = lane & 15;
  const int arow = (wv*16 + l16)*136 + quad*8;
  const int brow_base = l16*HIDC + quad*8;   // + ft*16*HIDC + ks*32

  // MFMA loop 1: M @ W1^T (B from global)
  f32x4 acc[8];
#pragma unroll
  for (int ft = 0; ft < 8; ++ft) acc[ft] = (f32x4){0.f,0.f,0.f,0.f};
#pragma unroll
  for (int ks = 0; ks < 4; ++ks) {
    bf16x8 a = *(const bf16x8*)(const void*)&Ab[arow + ks*32];
#pragma unroll
    for (int ft = 0; ft < 8; ++ft) {
      bf16x8 b = *(const bf16x8*)&W1b[brow_base + ft*16*HIDC + ks*32];
      acc[ft] = __builtin_amdgcn_mfma_f32_16x16x32_bf16(a, b, acc[ft], 0, 0, 0);
    }
  }

  // epilogue 1: bias + relu + LN -> T in Ab
  {
    float bb[8], gg[8], bee[8];
#pragma unroll
    for (int ft = 0; ft < 8; ++ft) {
      int f = ft*16 + l16;
      bb[ft] = b1[f]; gg[ft] = g1[f]; bee[ft] = be1[f];
    }
    float s1[4] = {0,0,0,0}, s2[4] = {0,0,0,0};
#pragma unroll
    for (int ft = 0; ft < 8; ++ft)
#pragma unroll
      for (int r = 0; r < 4; ++r) {
        float v = fmaxf(acc[ft][r] + bb[ft], 0.f);
        acc[ft][r] = v; s1[r] += v; s2[r] += v*v;
      }
#pragma unroll
    for (int m = 1; m < 16; m <<= 1)
#pragma unroll
      for (int r = 0; r < 4; ++r) {
        s1[r] += __shfl_xor(s1[r], m);
        s2[r] += __shfl_xor(s2[r], m);
      }
    float mu[4], rs[4];
#pragma unroll
    for (int r = 0; r < 4; ++r) {
      mu[r] = s1[r] * (1.f/128.f);
      float var = fmaxf(s2[r] * (1.f/128.f) - mu[r]*mu[r], 0.f);
      rs[r] = rsqrtf(var + LN_EPSF);
    }
    __syncthreads();
#pragma unroll
    for (int r = 0; r < 4; ++r) {
      int nloc = wv*16 + quad*4 + r;
#pragma unroll
      for (int ft = 0; ft < 8; ++ft) {
        float o = (acc[ft][r] - mu[r])*rs[r]*gg[ft] + bee[ft];
        Ab[nloc*136 + ft*16 + l16] = f2bf(o);
      }
    }
  }
  __syncthreads();

  // MFMA loop 2: T @ W2^T (B from global)
#pragma unroll
  for (int ft = 0; ft < 8; ++ft) acc[ft] = (f32x4){0.f,0.f,0.f,0.f};
#pragma unroll
  for (int ks = 0; ks < 4; ++ks) {
    bf16x8 a = *(const bf16x8*)(const void*)&Ab[arow + ks*32];
#pragma unroll
    for (int ft = 0; ft < 8; ++ft) {
      bf16x8 b = *(const bf16x8*)&W2b[brow_base + ft*16*HIDC + ks*32];
      acc[ft] = __builtin_amdgcn_mfma_f32_16x16x32_bf16(a, b, acc[ft], 0, 0, 0);
    }
  }

  // epilogue 2: bias + relu + LN -> Ab
  {
    float bb[8], gg[8], bee[8];
#pragma unroll
    for (int ft = 0; ft < 8; ++ft) {
      int f = ft*16 + l16;
      bb[ft] = b2[f]; gg[ft] = lng[f]; bee[ft] = lnb[f];
    }
    float s1[4] = {0,0,0,0}, s2[4] = {0,0,0,0};
#pragma unroll
    for (int ft = 0; ft < 8; ++ft)
#pragma unroll
      for (int r = 0; r < 4; ++r) {
        float v = fmaxf(acc[ft][r] + bb[ft], 0.f);
        acc[ft][r] = v; s1[r] += v; s2[r] += v*v;
      }
#pragma unroll
    for (int m = 1; m < 16; m <<= 1)
#pragma unroll
      for (int r = 0; r < 4; ++r) {
        s1[r] += __shfl_xor(s1[r], m);
        s2[r] += __shfl_xor(s2[r], m);
      }
    float mu[4], rs[4];
#pragma unroll
    for (int r = 0; r < 4; ++r) {
      mu[r] = s1[r] * (1.f/128.f);
      float var = fmaxf(s2[r] * (1.f/128.f) - mu[r]*mu[r], 0.f);
      rs[r] = rsqrtf(var + LN_EPSF);
    }
    __syncthreads();
#pragma unroll
    for (int r = 0; r < 4; ++r) {
      int nloc = wv*16 + quad*4 + r;
#pragma unroll
      for (int ft = 0; ft < 8; ++ft) {
        float o = (acc[ft][r] - mu[r])*rs[r]*gg[ft] + bee[ft];
        Ab[nloc*136 + ft*16 + l16] = f2bf(o);
      }
    }
  }
  __syncthreads();
  // final store: + residual (Hin row), coalesced 16B chunks
#pragma unroll
  for (int i = 0; i < 4; ++i) {
    int chunk = t + i*256;
    int n = chunk >> 4, cc = chunk & 15;
    int gn = nb + n;
    if (gn >= N_NODESC) continue;
    bf16x8 vv = *(const bf16x8*)&Ab[n*136 + cc*8];
    bf16x8 rr = *(const bf16x8*)&Hin[gn*HIDC + cc*8];
    bf16x8 o8;
#pragma unroll
    for (int k = 0; k < 8; ++k)
      o8[k] = (short)f2bf(bf2f((unsigned short)vv[k]) + bf2f((unsigned short)rr[k]));
    *(bf16x8*)&Hout[gn*HIDC + cc*8] = o8;
  }
}

// ---------- MFMA gate + inline per-graph max ----------
__global__ __launch_bounds__(256, 4) void gate_mfma_kernel(
    const unsigned short* __restrict__ Hb, const float* __restrict__ W1,
    const float* __restrict__ b1, const float* __restrict__ lng,
    const float* __restrict__ lnb, const float* __restrict__ W2,
    const float* __restrict__ b2, const int* __restrict__ batch,
    float* __restrict__ gateb, unsigned* __restrict__ gmaxu) {
  __shared__ unsigned short Ab[64*136];
  __shared__ unsigned short Wl[64*136];
  __shared__ unsigned sgm[N_GRAPHSC];
  const int t = threadIdx.x;
  const int nb = blockIdx.x * 64;
  if (t < N_GRAPHSC) sgm[t] = 0u;
#pragma unroll
  for (int i = 0; i < 4; ++i) {
    int chunk = t + i*256;
    int n = chunk >> 4, c8 = chunk & 15;
    int gn = nb + n;
    bf16x8 v = {0,0,0,0,0,0,0,0};
    if (gn < N_NODESC) v = *(const bf16x8*)&Hb[gn*HIDC + c8*8];
    *(bf16x8*)&Ab[n*136 + c8*8] = v;
  }
#pragma unroll
  for (int i = 0; i < 8; ++i) {
    int q = t + i*256;
    int f = q >> 5, c4 = q & 31;
    float4 v = *(const float4*)&W1[f*HIDC + c4*4];
    ushort4 h;
    h.x = f2bf(v.x); h.y = f2bf(v.y); h.z = f2bf(v.z); h.w = f2bf(v.w);
    *(ushort4*)&Wl[f*136 + c4*4] = h;
  }
  __syncthreads();

  const int lane = t & 63, wv = t >> 6;
  const int quad = lane >> 4, l16 = lane & 15;
  f32x4 acc[4];
#pragma unroll
  for (int ft = 0; ft < 4; ++ft) acc[ft] = (f32x4){0.f,0.f,0.f,0.f};

  const int arow = (wv*16 + l16)*136 + quad*8;
#pragma unroll
  for (int ks = 0; ks < 4; ++ks) {
    bf16x8 a = *(const bf16x8*)(const void*)&Ab[arow + ks*32];
#pragma unroll
    for (int ft = 0; ft < 4; ++ft) {
      bf16x8 b = *(const bf16x8*)(const void*)&Wl[(ft*16 + l16)*136 + quad*8 + ks*32];
      acc[ft] = __builtin_amdgcn_mfma_f32_16x16x32_bf16(a, b, acc[ft], 0, 0, 0);
    }
  }

  float bb[4], gg[4], bee[4], w2v[4];
#pragma unroll
  for (int ft = 0; ft < 4; ++ft) {
    int f = ft*16 + l16;
    bb[ft] = b1[f]; gg[ft] = lng[f]; bee[ft] = lnb[f]; w2v[ft] = W2[f];
  }
  float s1[4] = {0,0,0,0}, s2[4] = {0,0,0,0};
#pragma unroll
  for (int ft = 0; ft < 4; ++ft)
#pragma unroll
    for (int r = 0; r < 4; ++r) {
      float v = fmaxf(acc[ft][r] + bb[ft], 0.f);
      acc[ft][r] = v; s1[r] += v; s2[r] += v*v;
    }
#pragma unroll
  for (int m = 1; m < 16; m <<= 1)
#pragma unroll
    for (int r = 0; r < 4; ++r) {
      s1[r] += __shfl_xor(s1[r], m);
      s2[r] += __shfl_xor(s2[r], m);
    }
  float pd[4];
#pragma unroll
  for (int r = 0; r < 4; ++r) {
    float mu = s1[r] * (1.f/64.f);
    float var = fmaxf(s2[r] * (1.f/64.f) - mu*mu, 0.f);
    float rs = rsqrtf(var + LN_EPSF);
    float p = 0.f;
#pragma unroll
    for (int ft = 0; ft < 4; ++ft)
      p += ((acc[ft][r] - mu)*rs*gg[ft] + bee[ft]) * w2v[ft];
    pd[r] = p;
  }
#pragma unroll
  for (int m = 1; m < 16; m <<= 1)
#pragma unroll
    for (int r = 0; r < 4; ++r) pd[r] += __shfl_xor(pd[r], m);
  if (l16 == 0) {
    float b2v = b2[0];
#pragma unroll
    for (int r = 0; r < 4; ++r) {
      int node = nb + wv*16 + quad*4 + r;
      if (node < N_NODESC) {
        float gv = pd[r] + b2v;
        gateb[node] = gv;
        atomicMax(&sgm[batch[node]], ord_enc(gv));
      }
    }
  }
  __syncthreads();
  if (t < N_GRAPHSC && sgm[t] != 0u) atomicMax(&gmaxu[t], sgm[t]);
}

// ---------- segmented softmax-weighted pooling (bf16 H) ----------
__global__ __launch_bounds__(256) void pool_kernel(const unsigned short* __restrict__ Hb,
    const float* __restrict__ gateb, const int* __restrict__ gstart,
    const unsigned* __restrict__ gmaxu, float* __restrict__ S,
    float* __restrict__ denom) {
  const int g    = blockIdx.x / POOL_SPLIT;
  const int part = blockIdx.x % POOL_SPLIT;
  const int s0 = gstart[g], s1 = gstart[g+1];
  const int cnt = s1 - s0;
  const int chunk = (cnt + POOL_SPLIT - 1) / POOL_SPLIT;
  int lo = s0 + part * chunk;
  int hi = lo + chunk; if (hi > s1) hi = s1;
  const int t = threadIdx.x;
  const int c8 = t & 15;
  const int v  = t >> 4;
  const float gm = ord_dec(gmaxu[g]);
  float acc[8];
#pragma unroll
  for (int k = 0; k < 8; ++k) acc[k] = 0.f;
  float de = 0.f;
  for (int n = lo + v; n < hi; n += 16) {
    float e = expf(gateb[n] - gm);
    bf16x8 hv = *(const bf16x8*)&Hb[n*HIDC + c8*8];
#pragma unroll
    for (int k = 0; k < 8; ++k) acc[k] += e * bf2f((unsigned short)hv[k]);
    if (c8 == 0) de += e;
  }
  __shared__ float sacc[16*128];
  __shared__ float sden[16];
#pragma unroll
  for (int k = 0; k < 8; ++k) sacc[v*128 + c8*8 + k] = acc[k];
  if (c8 == 0) sden[v] = de;
  __syncthreads();
  if (t < 128) {
    float s = 0.f;
#pragma unroll
    for (int vv = 0; vv < 16; ++vv) s += sacc[vv*128 + t];
    atomicAdd(&S[g*HIDC + t], s);
  }
  if (t == 0) {
    float d = 0.f;
#pragma unroll
    for (int vv = 0; vv < 16; ++vv) d += sden[vv];
    atomicAdd(&denom[g], d);
  }
}

// ---------- head MLP per graph ----------
__global__ __launch_bounds__(64) void head_kernel(const float* __restrict__ S,
    const float* __restrict__ denom, const float* __restrict__ W1,
    const float* __restrict__ b1, const float* __restrict__ g,
    const float* __restrict__ be, const float* __restrict__ W2,
    const float* __restrict__ b2, float* __restrict__ out) {
  const int gr = blockIdx.x;
  const int j = threadIdx.x;
  const float inv = 1.0f / denom[gr];
  float v = b1[j];
  for (int k = 0; k < HIDC; ++k) v += (S[gr*HIDC + k] * inv) * W1[j*HIDC + k];
  v = fmaxf(v, 0.f);
  float s1 = v, s2 = v*v;
  for (int off = 32; off; off >>= 1) { s1 += __shfl_xor(s1, off); s2 += __shfl_xor(s2, off); }
  float mu = s1 * (1.f/64.f);
  float var = fmaxf(s2 * (1.f/64.f) - mu*mu, 0.f);
  float rs = rsqrtf(var + LN_EPSF);
  float z = (v-mu)*rs*g[j] + be[j];
  float p = z * W2[j];
  for (int off = 32; off; off >>= 1) p += __shfl_xor(p, off);
  if (j == 0) out[gr] = p + b2[0];
}

// ---------- launch ----------
extern "C" void kernel_launch(void* const* d_in, const int* in_sizes, int n_in,
                              void* d_out, int out_size, void* d_ws, size_t ws_size,
                              hipStream_t stream) {
  (void)in_sizes; (void)n_in; (void)out_size; (void)ws_size;
  const float* x     = (const float*)d_in[0];
  const int*   ei    = (const int*)d_in[1];
  const int*   batch = (const int*)d_in[2];
  const float* aW1 = (const float*)d_in[3];
  const float* ab1 = (const float*)d_in[4];
  const float* ag  = (const float*)d_in[5];
  const float* abe = (const float*)d_in[6];
  const float* aW2 = (const float*)d_in[7];
  const float* ab2 = (const float*)d_in[8];
  const float* oW1 = (const float*)d_in[9];
  const float* ob1 = (const float*)d_in[10];
  const float* og  = (const float*)d_in[11];
  const float* obe = (const float*)d_in[12];
  const float* oW2 = (const float*)d_in[13];
  const float* ob2 = (const float*)d_in[14];
  const float* ninW = (const float*)d_in[15];
  const float* ninb = (const float*)d_in[16];
  const float* cW1 = (const float*)d_in[17];
  const float* cb1 = (const float*)d_in[18];
  const float* cg  = (const float*)d_in[19];
  const float* cbe = (const float*)d_in[20];
  const float* cW2 = (const float*)d_in[21];
  const float* cb2 = (const float*)d_in[22];
  const float* eps = (const float*)d_in[23];
  const float* lng = (const float*)d_in[24];
  const float* lnb = (const float*)d_in[25];
  const float* gW1 = (const float*)d_in[26];
  const float* gb1 = (const float*)d_in[27];
  const float* gg  = (const float*)d_in[28];
  const float* gbe = (const float*)d_in[29];
  const float* gW2 = (const float*)d_in[30];
  const float* gb2 = (const float*)d_in[31];
  const float* hW1 = (const float*)d_in[32];
  const float* hb1 = (const float*)d_in[33];
  const float* hg  = (const float*)d_in[34];
  const float* hbe = (const float*)d_in[35];
  const float* hW2 = (const float*)d_in[36];
  const float* hb2 = (const float*)d_in[37];

  char* ws = (char*)d_ws;
  unsigned short* Ha = (unsigned short*)(ws + 0);          // 12,800,000 B
  unsigned short* Hc = (unsigned short*)(ws + 12800000);   // 12,800,000 B
  unsigned short* Mb = (unsigned short*)(ws + 25600000);   // 12,800,000 B
  float* gateb = (float*)(ws + 38400000);                  // 200,000 B
  // --- contiguous zero region: deg | S | denom | gmaxu ---
  int*   deg   = (int*)(ws + 38600000);                    // 200,000 B
  float* S     = (float*)(ws + 38800000);                  // 32,768 B
  float* denom = (float*)(ws + 38832768);                  // 256 B
  unsigned* gmaxu = (unsigned*)(ws + 38833024);            // 256 B
  // -------------------------------------------------------
  int* rowptr  = (int*)(ws + 38833280);                    // 200,004 B
  int* cursor  = (int*)(ws + 39033284);                    // 200,000 B
  int* esrc    = (int*)(ws + 39233284);                    // 2,560,000 B
  int* bsum    = (int*)(ws + 41793284);                    // 256 B
  int* gstart  = (int*)(ws + 41793540);                    // 260 B
  unsigned short* ninWb = (unsigned short*)(ws + 41800000);// 16,384 B
  unsigned short* cW1b  = (unsigned short*)(ws + 41816384);// 98,304 B
  unsigned short* cW2b  = (unsigned short*)(ws + 41914688);// 98,304 B

  hipMemsetAsync(deg, 0, 233280, stream);  // deg + S + denom + gmaxu

  hist_gbound_kernel<<<EGRID + NGRID_GB + WPREP_NB, 256, 0, stream>>>(
      ei, deg, batch, gstart, ninW, ninWb, cW1, cW1b, cW2, cW2b);
  scan1_kernel<<<SCAN_NB, 1024, 0, stream>>>(deg, rowptr, bsum);
  scan23_kernel<<<SCAN_NB, 1024, 0, stream>>>(deg, bsum, rowptr, cursor);
  scatter_kernel<<<EGRID, 256, 0, stream>>>(ei, cursor, esrc);

  const int ngrid64 = (N_NODESC + 63) / 64;
  enc_mfma_kernel<<<ngrid64, 256, 0, stream>>>(x, aW1, ab1, ag, abe, aW2, ab2,
                                               oW1, ob1, og, obe, oW2, ob2,
                                               ninWb, ninb, Ha);
  unsigned short* cur = Ha;
  unsigned short* nxt = Hc;
  for (int l = 0; l < 3; ++l) {
    agg_kernel<<<(N_NODESC + 7) / 8, 128, 0, stream>>>(cur, rowptr, esrc, eps + l, Mb);
    gemmpair_kernel<<<ngrid64, 256, 0, stream>>>(
        Mb, cur,
        cW1b + l*HIDC*HIDC, cb1 + l*HIDC, cg + l*HIDC, cbe + l*HIDC,
        cW2b + l*HIDC*HIDC, cb2 + l*HIDC, lng + l*HIDC, lnb + l*HIDC,
        nxt);
    unsigned short* tmp = cur; cur = nxt; nxt = tmp;
  }
  // after 3 layers, cur == Hc holds the final H
  gate_mfma_kernel<<<ngrid64, 256, 0, stream>>>(cur, gW1, gb1, gg, gbe, gW2, gb2,
                                                batch, gateb, gmaxu);
  pool_kernel<<<N_GRAPHSC * POOL_SPLIT, 256, 0, stream>>>(cur, gateb, gstart, gmaxu, S, denom);
  head_kernel<<<N_GRAPHSC, 64, 0, stream>>>(S, denom, hW1, hb1, hg, hbe, hW2, hb2,
                                            (float*)d_out);
}

// Round 14
// 372.539 us; speedup vs baseline: 1.1315x; 1.1315x over previous
//
#include <hip/hip_runtime.h>

#define N_NODESC 50000
#define N_EDGESC 640000
#define N_GRAPHSC 64
#define HIDC 128
#define LN_EPSF 1e-5f
#define POOL_SPLIT 16
#define SCAN_NB 49   // 49*1024 = 50176 >= 50000
#define EGRID ((N_EDGESC + 255) / 256)
#define NGRID_GB ((N_NODESC + 255) / 256)
#define PREP_ELEMS (8192 + 49152 + 49152)   // ninWb + cW1b + cW2b
#define WPREP_NB ((PREP_ELEMS + 255) / 256) // 416

typedef short bf16x8 __attribute__((ext_vector_type(8)));
typedef float f32x4 __attribute__((ext_vector_type(4)));

// ---------- helpers ----------
static __device__ __forceinline__ unsigned ord_enc(float f) {
  unsigned u = __float_as_uint(f);
  return (u & 0x80000000u) ? ~u : (u | 0x80000000u);
}
static __device__ __forceinline__ float ord_dec(unsigned u) {
  return __uint_as_float((u & 0x80000000u) ? (u ^ 0x80000000u) : ~u);
}
static __device__ __forceinline__ unsigned short f2bf(float x) {
  unsigned u = __float_as_uint(x);
  u += 0x7fffu + ((u >> 16) & 1u);
  return (unsigned short)(u >> 16);
}
static __device__ __forceinline__ float bf2f(unsigned short b) {
  return __uint_as_float(((unsigned)b) << 16);
}

static __device__ __forceinline__ void mlp16(float in0, float in1, float in2,
    const float* __restrict__ W1, const float* __restrict__ b1,
    const float* __restrict__ g, const float* __restrict__ be,
    const float* __restrict__ W2, const float* __restrict__ b2,
    float* __restrict__ out) {
  float h[16];
  float s1 = 0.f, s2 = 0.f;
#pragma unroll
  for (int j = 0; j < 16; ++j) {
    float v = b1[j] + W1[j*3+0]*in0 + W1[j*3+1]*in1 + W1[j*3+2]*in2;
    v = fmaxf(v, 0.f);
    h[j] = v; s1 += v; s2 += v*v;
  }
  float mu = s1 * (1.f/16.f);
  float var = fmaxf(s2 * (1.f/16.f) - mu*mu, 0.f);
  float rs = rsqrtf(var + LN_EPSF);
  float z[16];
#pragma unroll
  for (int j = 0; j < 16; ++j) z[j] = (h[j]-mu)*rs*g[j] + be[j];
#pragma unroll
  for (int j = 0; j < 16; ++j) {
    float v = b2[j];
#pragma unroll
    for (int k = 0; k < 16; ++k) v += W2[j*16+k]*z[k];
    out[j] = v;
  }
}

// ---------- hist (edges) + gbound (nodes) + weight bf16 prep in one dispatch ----------
__global__ __launch_bounds__(256) void hist_gbound_kernel(const int* __restrict__ ei,
    int* __restrict__ deg, const int* __restrict__ batch, int* __restrict__ gstart,
    const float* __restrict__ ninW, unsigned short* __restrict__ ninWb,
    const float* __restrict__ cW1, unsigned short* __restrict__ cW1b,
    const float* __restrict__ cW2, unsigned short* __restrict__ cW2b) {
  const int b = blockIdx.x;
  if (b < EGRID) {
    int e = b * 256 + threadIdx.x;
    if (e < N_EDGESC) atomicAdd(&deg[ei[N_EDGESC + e]], 1);
  } else if (b < EGRID + NGRID_GB) {
    int i = (b - EGRID) * 256 + threadIdx.x;
    if (i >= N_NODESC) return;
    int bb = batch[i];
    int prev = (i == 0) ? -1 : batch[i-1];
    for (int g = prev + 1; g <= bb; ++g) gstart[g] = i;
    if (i == N_NODESC - 1) {
      for (int g = bb + 1; g <= N_GRAPHSC; ++g) gstart[g] = N_NODESC;
    }
  } else {
    int i = (b - EGRID - NGRID_GB) * 256 + threadIdx.x;
    if (i < 8192) {
      int f = i >> 6, k = i & 63;
      ninWb[i] = (k < 45) ? f2bf(ninW[f*45 + k]) : (unsigned short)0;
    } else if (i < 8192 + 49152) {
      int j = i - 8192;
      cW1b[j] = f2bf(cW1[j]);
    } else if (i < PREP_ELEMS) {
      int j = i - 8192 - 49152;
      cW2b[j] = f2bf(cW2[j]);
    }
  }
}

// ---------- scan phase 1 ----------
__global__ __launch_bounds__(1024) void scan1_kernel(const int* __restrict__ deg,
                                                     int* __restrict__ incl,
                                                     int* __restrict__ bsum) {
  const int b = blockIdx.x, t = threadIdx.x;
  const int i = b * 1024 + t;
  const int lane = t & 63, w = t >> 6;
  int v = (i < N_NODESC) ? deg[i] : 0;
#pragma unroll
  for (int off = 1; off < 64; off <<= 1) {
    int n = __shfl_up(v, off);
    if (lane >= off) v += n;
  }
  __shared__ int wsum[16];
  if (lane == 63) wsum[w] = v;
  __syncthreads();
  if (t == 0) {
    int run = 0;
#pragma unroll
    for (int k = 0; k < 16; ++k) { int x = wsum[k]; wsum[k] = run; run += x; }
  }
  __syncthreads();
  v += wsum[w];
  if (i < N_NODESC) incl[i] = v;
  if (t == 1023) bsum[b] = v;
}

// ---------- scan phases 2+3 fused ----------
__global__ __launch_bounds__(1024) void scan23_kernel(const int* __restrict__ deg,
                                                      const int* __restrict__ bsum,
                                                      int* __restrict__ rowptr,
                                                      int* __restrict__ cursor) {
  __shared__ int ex[SCAN_NB + 1];
  const int b = blockIdx.x, t = threadIdx.x;
  if (t < 64) {
    int v = (t < SCAN_NB) ? bsum[t] : 0;
    const int orig = v;
#pragma unroll
    for (int off = 1; off < 64; off <<= 1) {
      int n = __shfl_up(v, off);
      if (t >= off) v += n;
    }
    if (t < SCAN_NB) ex[t] = v - orig;
    if (t == SCAN_NB - 1) ex[SCAN_NB] = v;
  }
  __syncthreads();
  const int i = b * 1024 + t;
  if (i < N_NODESC) {
    int excl = rowptr[i] - deg[i] + ex[b];
    rowptr[i] = excl;
    cursor[i] = excl;
  }
  if (b == 0 && t == 0) rowptr[N_NODESC] = ex[SCAN_NB];
}

__global__ __launch_bounds__(256) void scatter_kernel(const int* __restrict__ ei,
                                                      int* __restrict__ cursor,
                                                      int* __restrict__ esrc) {
  int e = blockIdx.x * 256 + threadIdx.x;
  if (e < N_EDGESC) {
    int d = ei[N_EDGESC + e];
    int slot = atomicAdd(&cursor[d], 1);
    esrc[slot] = ei[e];
  }
}

// ---------- encoder (MFMA): parallel small MLPs -> bf16 A tile -> MFMA vs ninWb ----------
__global__ __launch_bounds__(256, 4) void enc_mfma_kernel(
    const float* __restrict__ x,
    const float* __restrict__ aW1, const float* __restrict__ ab1,
    const float* __restrict__ ag,  const float* __restrict__ abe,
    const float* __restrict__ aW2, const float* __restrict__ ab2,
    const float* __restrict__ oW1, const float* __restrict__ ob1,
    const float* __restrict__ og,  const float* __restrict__ obe,
    const float* __restrict__ oW2, const float* __restrict__ ob2,
    const unsigned short* __restrict__ ninWb, const float* __restrict__ ninb,
    unsigned short* __restrict__ Hb) {
  __shared__ unsigned short Ab[64*136];
  const int t = threadIdx.x;
  const int nb = blockIdx.x * 64;

  if (t < 192) {
    const int n = t & 63;
    const int gn = nb + n;
    const int grp = t >> 6;
    if (gn < N_NODESC) {
      const float* xr = x + gn * 19;
      if (grp == 0) {
        float z[16];
        mlp16(xr[9], xr[10], xr[11], aW1, ab1, ag, abe, aW2, ab2, z);
#pragma unroll
        for (int k = 0; k < 16; ++k) Ab[n*136 + 13 + k] = f2bf(z[k]);
      } else if (grp == 1) {
        float z[16];
        mlp16(xr[12], xr[13], xr[14], oW1, ob1, og, obe, oW2, ob2, z);
#pragma unroll
        for (int k = 0; k < 16; ++k) Ab[n*136 + 29 + k] = f2bf(z[k]);
      } else {
#pragma unroll
        for (int k = 0; k < 9; ++k) Ab[n*136 + k] = f2bf(xr[k]);
#pragma unroll
        for (int k = 0; k < 4; ++k) Ab[n*136 + 9 + k] = f2bf(xr[15 + k]);
#pragma unroll
        for (int k = 45; k < 64; ++k) Ab[n*136 + k] = 0;
      }
    } else {
      if (grp == 0) {
#pragma unroll
        for (int k = 0; k < 16; ++k) Ab[n*136 + 13 + k] = 0;
      } else if (grp == 1) {
#pragma unroll
        for (int k = 0; k < 16; ++k) Ab[n*136 + 29 + k] = 0;
      } else {
#pragma unroll
        for (int k = 0; k < 13; ++k) Ab[n*136 + k] = 0;
#pragma unroll
        for (int k = 45; k < 64; ++k) Ab[n*136 + k] = 0;
      }
    }
  }
  __syncthreads();

  const int lane = t & 63, wv = t >> 6;
  const int quad = lane >> 4, l16 = lane & 15;
  const int arow = (wv*16 + l16)*136 + quad*8;
  f32x4 acc[8];
#pragma unroll
  for (int ft = 0; ft < 8; ++ft) acc[ft] = (f32x4){0.f,0.f,0.f,0.f};
#pragma unroll
  for (int ks = 0; ks < 2; ++ks) {
    bf16x8 a = *(const bf16x8*)(const void*)&Ab[arow + ks*32];
#pragma unroll
    for (int ft = 0; ft < 8; ++ft) {
      bf16x8 bfr = *(const bf16x8*)&ninWb[(ft*16 + l16)*64 + quad*8 + ks*32];
      acc[ft] = __builtin_amdgcn_mfma_f32_16x16x32_bf16(a, bfr, acc[ft], 0, 0, 0);
    }
  }
  float bb[8];
#pragma unroll
  for (int ft = 0; ft < 8; ++ft) bb[ft] = ninb[ft*16 + l16];
  __syncthreads();
#pragma unroll
  for (int r = 0; r < 4; ++r) {
    int nloc = wv*16 + quad*4 + r;
#pragma unroll
    for (int ft = 0; ft < 8; ++ft)
      Ab[nloc*136 + ft*16 + l16] = f2bf(acc[ft][r] + bb[ft]);
  }
  __syncthreads();
#pragma unroll
  for (int i = 0; i < 4; ++i) {
    int chunk = t + i*256;
    int n = chunk >> 4, c8 = chunk & 15;
    int gn = nb + n;
    if (gn < N_NODESC)
      *(bf16x8*)&Hb[gn*HIDC + c8*8] = *(const bf16x8*)&Ab[n*136 + c8*8];
  }
}

// ---------- aggregation (bf16, standalone for max gather parallelism) ----------
__global__ __launch_bounds__(128) void agg_kernel(const unsigned short* __restrict__ Hb,
    const int* __restrict__ rowptr, const int* __restrict__ esrc,
    const float* __restrict__ epsp, unsigned short* __restrict__ Mb) {
  const int t = threadIdx.x;
  const int c8 = t & 15;
  const int v  = t >> 4;
  const int node = blockIdx.x * 8 + v;
  if (node >= N_NODESC) return;
  const float e1 = 1.0f + epsp[0];
  bf16x8 h = *(const bf16x8*)&Hb[node*HIDC + c8*8];
  float acc[8];
#pragma unroll
  for (int k = 0; k < 8; ++k) acc[k] = 0.f;
  int s = rowptr[node];
  const int e = rowptr[node+1];
  for (; s + 4 <= e; s += 4) {
    int i0 = esrc[s], i1 = esrc[s+1], i2 = esrc[s+2], i3 = esrc[s+3];
    bf16x8 x0 = *(const bf16x8*)&Hb[i0*HIDC + c8*8];
    bf16x8 x1 = *(const bf16x8*)&Hb[i1*HIDC + c8*8];
    bf16x8 x2 = *(const bf16x8*)&Hb[i2*HIDC + c8*8];
    bf16x8 x3 = *(const bf16x8*)&Hb[i3*HIDC + c8*8];
#pragma unroll
    for (int k = 0; k < 8; ++k)
      acc[k] += (bf2f((unsigned short)x0[k]) + bf2f((unsigned short)x1[k]))
              + (bf2f((unsigned short)x2[k]) + bf2f((unsigned short)x3[k]));
  }
  for (; s < e; ++s) {
    bf16x8 x0 = *(const bf16x8*)&Hb[esrc[s]*HIDC + c8*8];
#pragma unroll
    for (int k = 0; k < 8; ++k) acc[k] += bf2f((unsigned short)x0[k]);
  }
  bf16x8 m8;
#pragma unroll
  for (int k = 0; k < 8; ++k)
    m8[k] = (short)f2bf(e1*bf2f((unsigned short)h[k]) + acc[k]);
  *(bf16x8*)&Mb[node*HIDC + c8*8] = m8;
}

// ---------- GEMM pair: T = LN(relu(M@W1^T+b1)); H' = LN(relu(T@W2^T+b2)) + Hin ----------
// T never leaves LDS. W staged from pre-converted bf16 into LDS (proven config).
__global__ __launch_bounds__(256, 3) void gemmpair_kernel(
    const unsigned short* __restrict__ Mb,
    const unsigned short* __restrict__ Hin,
    const unsigned short* __restrict__ W1b, const float* __restrict__ b1,
    const float* __restrict__ g1, const float* __restrict__ be1,
    const unsigned short* __restrict__ W2b, const float* __restrict__ b2,
    const float* __restrict__ lng, const float* __restrict__ lnb,
    unsigned short* __restrict__ Hout) {
  __shared__ unsigned short Ab[64*136];   // M tile -> T tile -> OUT tile
  __shared__ unsigned short Wl[128*136];  // W1 then W2 (bf16)
  const int t = threadIdx.x;
  const int nb = blockIdx.x * 64;

  // stage A tile from Mb
#pragma unroll
  for (int i = 0; i < 4; ++i) {
    int chunk = t + i*256;
    int n = chunk >> 4, c8 = chunk & 15;
    int gn = nb + n;
    bf16x8 v = {0,0,0,0,0,0,0,0};
    if (gn < N_NODESC) v = *(const bf16x8*)&Mb[gn*HIDC + c8*8];
    *(bf16x8*)&Ab[n*136 + c8*8] = v;
  }
  // stage W1 (bf16 straight copy, 16B chunks)
#pragma unroll
  for (int i = 0; i < 8; ++i) {
    int q = t + i*256;
    int f = q >> 4, c8 = q & 15;
    *(bf16x8*)&Wl[f*136 + c8*8] = *(const bf16x8*)&W1b[f*HIDC + c8*8];
  }
  __syncthreads();

  const int lane = t & 63, wv = t >> 6;
  const int quad = lane >> 4, l16 = lane & 15;
  const int arow = (wv*16 + l16)*136 + quad*8;

  // MFMA loop 1
  f32x4 acc[8];
#pragma unroll
  for (int ft = 0; ft < 8; ++ft) acc[ft] = (f32x4){0.f,0.f,0.f,0.f};
#pragma unroll
  for (int ks = 0; ks < 4; ++ks) {
    bf16x8 a = *(const bf16x8*)(const void*)&Ab[arow + ks*32];
#pragma unroll
    for (int ft = 0; ft < 8; ++ft) {
      bf16x8 b = *(const bf16x8*)(const void*)&Wl[(ft*16 + l16)*136 + quad*8 + ks*32];
      acc[ft] = __builtin_amdgcn_mfma_f32_16x16x32_bf16(a, b, acc[ft], 0, 0, 0);
    }
  }

  // epilogue 1: bias + relu + LN -> T in Ab
  {
    float bb[8], gg[8], bee[8];
#pragma unroll
    for (int ft = 0; ft < 8; ++ft) {
      int f = ft*16 + l16;
      bb[ft] = b1[f]; gg[ft] = g1[f]; bee[ft] = be1[f];
    }
    float s1[4] = {0,0,0,0}, s2[4] = {0,0,0,0};
#pragma unroll
    for (int ft = 0; ft < 8; ++ft)
#pragma unroll
      for (int r = 0; r < 4; ++r) {
        float v = fmaxf(acc[ft][r] + bb[ft], 0.f);
        acc[ft][r] = v; s1[r] += v; s2[r] += v*v;
      }
#pragma unroll
    for (int m = 1; m < 16; m <<= 1)
#pragma unroll
      for (int r = 0; r < 4; ++r) {
        s1[r] += __shfl_xor(s1[r], m);
        s2[r] += __shfl_xor(s2[r], m);
      }
    float mu[4], rs[4];
#pragma unroll
    for (int r = 0; r < 4; ++r) {
      mu[r] = s1[r] * (1.f/128.f);
      float var = fmaxf(s2[r] * (1.f/128.f) - mu[r]*mu[r], 0.f);
      rs[r] = rsqrtf(var + LN_EPSF);
    }
    __syncthreads();
#pragma unroll
    for (int r = 0; r < 4; ++r) {
      int nloc = wv*16 + quad*4 + r;
#pragma unroll
      for (int ft = 0; ft < 8; ++ft) {
        float o = (acc[ft][r] - mu[r])*rs[r]*gg[ft] + bee[ft];
        Ab[nloc*136 + ft*16 + l16] = f2bf(o);
      }
    }
  }
  // restage Wl = W2 (bf16)
#pragma unroll
  for (int i = 0; i < 8; ++i) {
    int q = t + i*256;
    int f = q >> 4, c8 = q & 15;
    *(bf16x8*)&Wl[f*136 + c8*8] = *(const bf16x8*)&W2b[f*HIDC + c8*8];
  }
  __syncthreads();

  // MFMA loop 2
#pragma unroll
  for (int ft = 0; ft < 8; ++ft) acc[ft] = (f32x4){0.f,0.f,0.f,0.f};
#pragma unroll
  for (int ks = 0; ks < 4; ++ks) {
    bf16x8 a = *(const bf16x8*)(const void*)&Ab[arow + ks*32];
#pragma unroll
    for (int ft = 0; ft < 8; ++ft) {
      bf16x8 b = *(const bf16x8*)(const void*)&Wl[(ft*16 + l16)*136 + quad*8 + ks*32];
      acc[ft] = __builtin_amdgcn_mfma_f32_16x16x32_bf16(a, b, acc[ft], 0, 0, 0);
    }
  }

  // epilogue 2: bias + relu + LN -> Ab
  {
    float bb[8], gg[8], bee[8];
#pragma unroll
    for (int ft = 0; ft < 8; ++ft) {
      int f = ft*16 + l16;
      bb[ft] = b2[f]; gg[ft] = lng[f]; bee[ft] = lnb[f];
    }
    float s1[4] = {0,0,0,0}, s2[4] = {0,0,0,0};
#pragma unroll
    for (int ft = 0; ft < 8; ++ft)
#pragma unroll
      for (int r = 0; r < 4; ++r) {
        float v = fmaxf(acc[ft][r] + bb[ft], 0.f);
        acc[ft][r] = v; s1[r] += v; s2[r] += v*v;
      }
#pragma unroll
    for (int m = 1; m < 16; m <<= 1)
#pragma unroll
      for (int r = 0; r < 4; ++r) {
        s1[r] += __shfl_xor(s1[r], m);
        s2[r] += __shfl_xor(s2[r], m);
      }
    float mu[4], rs[4];
#pragma unroll
    for (int r = 0; r < 4; ++r) {
      mu[r] = s1[r] * (1.f/128.f);
      float var = fmaxf(s2[r] * (1.f/128.f) - mu[r]*mu[r], 0.f);
      rs[r] = rsqrtf(var + LN_EPSF);
    }
    __syncthreads();
#pragma unroll
    for (int r = 0; r < 4; ++r) {
      int nloc = wv*16 + quad*4 + r;
#pragma unroll
      for (int ft = 0; ft < 8; ++ft) {
        float o = (acc[ft][r] - mu[r])*rs[r]*gg[ft] + bee[ft];
        Ab[nloc*136 + ft*16 + l16] = f2bf(o);
      }
    }
  }
  __syncthreads();
  // final store: + residual (Hin row), coalesced 16B chunks
#pragma unroll
  for (int i = 0; i < 4; ++i) {
    int chunk = t + i*256;
    int n = chunk >> 4, cc = chunk & 15;
    int gn = nb + n;
    if (gn >= N_NODESC) continue;
    bf16x8 vv = *(const bf16x8*)&Ab[n*136 + cc*8];
    bf16x8 rr = *(const bf16x8*)&Hin[gn*HIDC + cc*8];
    bf16x8 o8;
#pragma unroll
    for (int k = 0; k < 8; ++k)
      o8[k] = (short)f2bf(bf2f((unsigned short)vv[k]) + bf2f((unsigned short)rr[k]));
    *(bf16x8*)&Hout[gn*HIDC + cc*8] = o8;
  }
}

// ---------- MFMA gate + inline per-graph max ----------
__global__ __launch_bounds__(256, 4) void gate_mfma_kernel(
    const unsigned short* __restrict__ Hb, const float* __restrict__ W1,
    const float* __restrict__ b1, const float* __restrict__ lng,
    const float* __restrict__ lnb, const float* __restrict__ W2,
    const float* __restrict__ b2, const int* __restrict__ batch,
    float* __restrict__ gateb, unsigned* __restrict__ gmaxu) {
  __shared__ unsigned short Ab[64*136];
  __shared__ unsigned short Wl[64*136];
  __shared__ unsigned sgm[N_GRAPHSC];
  const int t = threadIdx.x;
  const int nb = blockIdx.x * 64;
  if (t < N_GRAPHSC) sgm[t] = 0u;
#pragma unroll
  for (int i = 0; i < 4; ++i) {
    int chunk = t + i*256;
    int n = chunk >> 4, c8 = chunk & 15;
    int gn = nb + n;
    bf16x8 v = {0,0,0,0,0,0,0,0};
    if (gn < N_NODESC) v = *(const bf16x8*)&Hb[gn*HIDC + c8*8];
    *(bf16x8*)&Ab[n*136 + c8*8] = v;
  }
#pragma unroll
  for (int i = 0; i < 8; ++i) {
    int q = t + i*256;
    int f = q >> 5, c4 = q & 31;
    float4 v = *(const float4*)&W1[f*HIDC + c4*4];
    ushort4 h;
    h.x = f2bf(v.x); h.y = f2bf(v.y); h.z = f2bf(v.z); h.w = f2bf(v.w);
    *(ushort4*)&Wl[f*136 + c4*4] = h;
  }
  __syncthreads();

  const int lane = t & 63, wv = t >> 6;
  const int quad = lane >> 4, l16 = lane & 15;
  f32x4 acc[4];
#pragma unroll
  for (int ft = 0; ft < 4; ++ft) acc[ft] = (f32x4){0.f,0.f,0.f,0.f};

  const int arow = (wv*16 + l16)*136 + quad*8;
#pragma unroll
  for (int ks = 0; ks < 4; ++ks) {
    bf16x8 a = *(const bf16x8*)(const void*)&Ab[arow + ks*32];
#pragma unroll
    for (int ft = 0; ft < 4; ++ft) {
      bf16x8 b = *(const bf16x8*)(const void*)&Wl[(ft*16 + l16)*136 + quad*8 + ks*32];
      acc[ft] = __builtin_amdgcn_mfma_f32_16x16x32_bf16(a, b, acc[ft], 0, 0, 0);
    }
  }

  float bb[4], gg[4], bee[4], w2v[4];
#pragma unroll
  for (int ft = 0; ft < 4; ++ft) {
    int f = ft*16 + l16;
    bb[ft] = b1[f]; gg[ft] = lng[f]; bee[ft] = lnb[f]; w2v[ft] = W2[f];
  }
  float s1[4] = {0,0,0,0}, s2[4] = {0,0,0,0};
#pragma unroll
  for (int ft = 0; ft < 4; ++ft)
#pragma unroll
    for (int r = 0; r < 4; ++r) {
      float v = fmaxf(acc[ft][r] + bb[ft], 0.f);
      acc[ft][r] = v; s1[r] += v; s2[r] += v*v;
    }
#pragma unroll
  for (int m = 1; m < 16; m <<= 1)
#pragma unroll
    for (int r = 0; r < 4; ++r) {
      s1[r] += __shfl_xor(s1[r], m);
      s2[r] += __shfl_xor(s2[r], m);
    }
  float pd[4];
#pragma unroll
  for (int r = 0; r < 4; ++r) {
    float mu = s1[r] * (1.f/64.f);
    float var = fmaxf(s2[r] * (1.f/64.f) - mu*mu, 0.f);
    float rs = rsqrtf(var + LN_EPSF);
    float p = 0.f;
#pragma unroll
    for (int ft = 0; ft < 4; ++ft)
      p += ((acc[ft][r] - mu)*rs*gg[ft] + bee[ft]) * w2v[ft];
    pd[r] = p;
  }
#pragma unroll
  for (int m = 1; m < 16; m <<= 1)
#pragma unroll
    for (int r = 0; r < 4; ++r) pd[r] += __shfl_xor(pd[r], m);
  if (l16 == 0) {
    float b2v = b2[0];
#pragma unroll
    for (int r = 0; r < 4; ++r) {
      int node = nb + wv*16 + quad*4 + r;
      if (node < N_NODESC) {
        float gv = pd[r] + b2v;
        gateb[node] = gv;
        atomicMax(&sgm[batch[node]], ord_enc(gv));
      }
    }
  }
  __syncthreads();
  if (t < N_GRAPHSC && sgm[t] != 0u) atomicMax(&gmaxu[t], sgm[t]);
}

// ---------- segmented softmax-weighted pooling (bf16 H) ----------
__global__ __launch_bounds__(256) void pool_kernel(const unsigned short* __restrict__ Hb,
    const float* __restrict__ gateb, const int* __restrict__ gstart,
    const unsigned* __restrict__ gmaxu, float* __restrict__ S,
    float* __restrict__ denom) {
  const int g    = blockIdx.x / POOL_SPLIT;
  const int part = blockIdx.x % POOL_SPLIT;
  const int s0 = gstart[g], s1 = gstart[g+1];
  const int cnt = s1 - s0;
  const int chunk = (cnt + POOL_SPLIT - 1) / POOL_SPLIT;
  int lo = s0 + part * chunk;
  int hi = lo + chunk; if (hi > s1) hi = s1;
  const int t = threadIdx.x;
  const int c8 = t & 15;
  const int v  = t >> 4;
  const float gm = ord_dec(gmaxu[g]);
  float acc[8];
#pragma unroll
  for (int k = 0; k < 8; ++k) acc[k] = 0.f;
  float de = 0.f;
  for (int n = lo + v; n < hi; n += 16) {
    float e = expf(gateb[n] - gm);
    bf16x8 hv = *(const bf16x8*)&Hb[n*HIDC + c8*8];
#pragma unroll
    for (int k = 0; k < 8; ++k) acc[k] += e * bf2f((unsigned short)hv[k]);
    if (c8 == 0) de += e;
  }
  __shared__ float sacc[16*128];
  __shared__ float sden[16];
#pragma unroll
  for (int k = 0; k < 8; ++k) sacc[v*128 + c8*8 + k] = acc[k];
  if (c8 == 0) sden[v] = de;
  __syncthreads();
  if (t < 128) {
    float s = 0.f;
#pragma unroll
    for (int vv = 0; vv < 16; ++vv) s += sacc[vv*128 + t];
    atomicAdd(&S[g*HIDC + t], s);
  }
  if (t == 0) {
    float d = 0.f;
#pragma unroll
    for (int vv = 0; vv < 16; ++vv) d += sden[vv];
    atomicAdd(&denom[g], d);
  }
}

// ---------- head MLP per graph ----------
__global__ __launch_bounds__(64) void head_kernel(const float* __restrict__ S,
    const float* __restrict__ denom, const float* __restrict__ W1,
    const float* __restrict__ b1, const float* __restrict__ g,
    const float* __restrict__ be, const float* __restrict__ W2,
    const float* __restrict__ b2, float* __restrict__ out) {
  const int gr = blockIdx.x;
  const int j = threadIdx.x;
  const float inv = 1.0f / denom[gr];
  float v = b1[j];
  for (int k = 0; k < HIDC; ++k) v += (S[gr*HIDC + k] * inv) * W1[j*HIDC + k];
  v = fmaxf(v, 0.f);
  float s1 = v, s2 = v*v;
  for (int off = 32; off; off >>= 1) { s1 += __shfl_xor(s1, off); s2 += __shfl_xor(s2, off); }
  float mu = s1 * (1.f/64.f);
  float var = fmaxf(s2 * (1.f/64.f) - mu*mu, 0.f);
  float rs = rsqrtf(var + LN_EPSF);
  float z = (v-mu)*rs*g[j] + be[j];
  float p = z * W2[j];
  for (int off = 32; off; off >>= 1) p += __shfl_xor(p, off);
  if (j == 0) out[gr] = p + b2[0];
}

// ---------- launch ----------
extern "C" void kernel_launch(void* const* d_in, const int* in_sizes, int n_in,
                              void* d_out, int out_size, void* d_ws, size_t ws_size,
                              hipStream_t stream) {
  (void)in_sizes; (void)n_in; (void)out_size; (void)ws_size;
  const float* x     = (const float*)d_in[0];
  const int*   ei    = (const int*)d_in[1];
  const int*   batch = (const int*)d_in[2];
  const float* aW1 = (const float*)d_in[3];
  const float* ab1 = (const float*)d_in[4];
  const float* ag  = (const float*)d_in[5];
  const float* abe = (const float*)d_in[6];
  const float* aW2 = (const float*)d_in[7];
  const float* ab2 = (const float*)d_in[8];
  const float* oW1 = (const float*)d_in[9];
  const float* ob1 = (const float*)d_in[10];
  const float* og  = (const float*)d_in[11];
  const float* obe = (const float*)d_in[12];
  const float* oW2 = (const float*)d_in[13];
  const float* ob2 = (const float*)d_in[14];
  const float* ninW = (const float*)d_in[15];
  const float* ninb = (const float*)d_in[16];
  const float* cW1 = (const float*)d_in[17];
  const float* cb1 = (const float*)d_in[18];
  const float* cg  = (const float*)d_in[19];
  const float* cbe = (const float*)d_in[20];
  const float* cW2 = (const float*)d_in[21];
  const float* cb2 = (const float*)d_in[22];
  const float* eps = (const float*)d_in[23];
  const float* lng = (const float*)d_in[24];
  const float* lnb = (const float*)d_in[25];
  const float* gW1 = (const float*)d_in[26];
  const float* gb1 = (const float*)d_in[27];
  const float* gg  = (const float*)d_in[28];
  const float* gbe = (const float*)d_in[29];
  const float* gW2 = (const float*)d_in[30];
  const float* gb2 = (const float*)d_in[31];
  const float* hW1 = (const float*)d_in[32];
  const float* hb1 = (const float*)d_in[33];
  const float* hg  = (const float*)d_in[34];
  const float* hbe = (const float*)d_in[35];
  const float* hW2 = (const float*)d_in[36];
  const float* hb2 = (const float*)d_in[37];

  char* ws = (char*)d_ws;
  unsigned short* Ha = (unsigned short*)(ws + 0);          // 12,800,000 B
  unsigned short* Hc = (unsigned short*)(ws + 12800000);   // 12,800,000 B
  unsigned short* Mb = (unsigned short*)(ws + 25600000);   // 12,800,000 B
  float* gateb = (float*)(ws + 38400000);                  // 200,000 B
  // --- contiguous zero region: deg | S | denom | gmaxu ---
  int*   deg   = (int*)(ws + 38600000);                    // 200,000 B
  float* S     = (float*)(ws + 38800000);                  // 32,768 B
  float* denom = (float*)(ws + 38832768);                  // 256 B
  unsigned* gmaxu = (unsigned*)(ws + 38833024);            // 256 B
  // -------------------------------------------------------
  int* rowptr  = (int*)(ws + 38833280);                    // 200,004 B
  int* cursor  = (int*)(ws + 39033284);                    // 200,000 B
  int* esrc    = (int*)(ws + 39233284);                    // 2,560,000 B
  int* bsum    = (int*)(ws + 41793284);                    // 256 B
  int* gstart  = (int*)(ws + 41793540);                    // 260 B
  unsigned short* ninWb = (unsigned short*)(ws + 41800000);// 16,384 B
  unsigned short* cW1b  = (unsigned short*)(ws + 41816384);// 98,304 B
  unsigned short* cW2b  = (unsigned short*)(ws + 41914688);// 98,304 B

  hipMemsetAsync(deg, 0, 233280, stream);  // deg + S + denom + gmaxu

  hist_gbound_kernel<<<EGRID + NGRID_GB + WPREP_NB, 256, 0, stream>>>(
      ei, deg, batch, gstart, ninW, ninWb, cW1, cW1b, cW2, cW2b);
  scan1_kernel<<<SCAN_NB, 1024, 0, stream>>>(deg, rowptr, bsum);
  scan23_kernel<<<SCAN_NB, 1024, 0, stream>>>(deg, bsum, rowptr, cursor);
  scatter_kernel<<<EGRID, 256, 0, stream>>>(ei, cursor, esrc);

  const int ngrid64 = (N_NODESC + 63) / 64;
  enc_mfma_kernel<<<ngrid64, 256, 0, stream>>>(x, aW1, ab1, ag, abe, aW2, ab2,
                                               oW1, ob1, og, obe, oW2, ob2,
                                               ninWb, ninb, Ha);
  unsigned short* cur = Ha;
  unsigned short* nxt = Hc;
  for (int l = 0; l < 3; ++l) {
    agg_kernel<<<(N_NODESC + 7) / 8, 128, 0, stream>>>(cur, rowptr, esrc, eps + l, Mb);
    gemmpair_kernel<<<ngrid64, 256, 0, stream>>>(
        Mb, cur,
        cW1b + l*HIDC*HIDC, cb1 + l*HIDC, cg + l*HIDC, cbe + l*HIDC,
        cW2b + l*HIDC*HIDC, cb2 + l*HIDC, lng + l*HIDC, lnb + l*HIDC,
        nxt);
    unsigned short* tmp = cur; cur = nxt; nxt = tmp;
  }
  // after 3 layers, cur == Hc holds the final H
  gate_mfma_kernel<<<ngrid64, 256, 0, stream>>>(cur, gW1, gb1, gg, gbe, gW2, gb2,
                                                batch, gateb, gmaxu);
  pool_kernel<<<N_GRAPHSC * POOL_SPLIT, 256, 0, stream>>>(cur, gateb, gstart, gmaxu, S, denom);
  head_kernel<<<N_GRAPHSC, 64, 0, stream>>>(S, denom, hW1, hb1, hg, hbe, hW2, hb2,
                                            (float*)d_out);
}